// Round 16
// baseline (312.002 us; speedup 1.0000x reference)
//
#include <hip/hip_runtime.h>
#include <hip/hip_bf16.h>

#define DIM 2048
#define SEQ 2048
#define HD 64
#define NH 32
#define NKV 8

typedef __bf16 bf16x8 __attribute__((ext_vector_type(8)));
typedef __bf16 bf16x4 __attribute__((ext_vector_type(4)));
typedef float f32x4 __attribute__((ext_vector_type(4)));
typedef float f32x16 __attribute__((ext_vector_type(16)));
typedef unsigned short ushortx8 __attribute__((ext_vector_type(8)));
typedef unsigned short ushortx4 __attribute__((ext_vector_type(4)));
typedef unsigned short ushort_t;

// Q pre-scale: 1/sqrt(64) * log2(e)  -> scores come out in exp2 domain
#define QSCALE 0.1803368801111f

// split-K chunking: 8 k-tiles (512 keys) per block; 128-row q-tiles
#define CHUNK 8
#define SLOTS_PER_H 40   // sum over qi=0..15 of ceil((2qi+2)/8)

// raw v_exp_f32 (single HW transcendental), not the ~30-instr OCML exp2f.
__device__ __forceinline__ float hexp2(float x) {
    return __builtin_amdgcn_exp2f(x);
}

__device__ __forceinline__ unsigned short f2bf(float f) {
    unsigned int u = __builtin_bit_cast(unsigned int, f);
    u = (u + 0x7FFFu + ((u >> 16) & 1u)) >> 16;   // round-to-nearest-even
    return (unsigned short)u;
}
__device__ __forceinline__ float bf2f(unsigned short h) {
    return __builtin_bit_cast(float, (unsigned int)h << 16);
}

__device__ __forceinline__ f32x4 mfma16(bf16x8 a, bf16x8 b, f32x4 c) {
    return __builtin_amdgcn_mfma_f32_16x16x32_bf16(a, b, c, 0, 0, 0);
}
__device__ __forceinline__ f32x16 mfma32(bf16x8 a, bf16x8 b, f32x16 c) {
    return __builtin_amdgcn_mfma_f32_32x32x16_bf16(a, b, c, 0, 0, 0);
}

// async global->LDS, 16 bytes per lane. LDS dest must be lane-contiguous.
__device__ __forceinline__ void gload16(const ushort_t* g, ushort_t* l) {
    __builtin_amdgcn_global_load_lds(
        (const __attribute__((address_space(1))) unsigned int*)g,
        (__attribute__((address_space(3))) unsigned int*)l, 16, 0, 0);
}

// ---------------------------------------------------------------------------
// fp32 -> bf16 conversion of all GEMM operands (one pass, memory-bound)
// ---------------------------------------------------------------------------
#define NX  (SEQ * DIM)
#define NWQ (DIM * DIM)
#define NWK (NKV * HD * DIM)
#define NWO (DIM * NH * HD)

__global__ __launch_bounds__(256)
void cvt5(const float* __restrict__ x, const float* __restrict__ wq,
          const float* __restrict__ wk, const float* __restrict__ wv,
          const float* __restrict__ wo,
          ushort_t* __restrict__ xb, ushort_t* __restrict__ wqb,
          ushort_t* __restrict__ wkb, ushort_t* __restrict__ wvb,
          ushort_t* __restrict__ wob)
{
    const int S0 = NX / 4, S1 = S0 + NWQ / 4, S2 = S1 + NWK / 4,
              S3 = S2 + NWK / 4, S4 = S3 + NWO / 4;
    for (int g = blockIdx.x * blockDim.x + threadIdx.x; g < S4;
         g += gridDim.x * blockDim.x) {
        const float* src; ushort_t* dst; int off;
        if (g < S0)      { src = x;  dst = xb;  off = g; }
        else if (g < S1) { src = wq; dst = wqb; off = g - S0; }
        else if (g < S2) { src = wk; dst = wkb; off = g - S1; }
        else if (g < S3) { src = wv; dst = wvb; off = g - S2; }
        else             { src = wo; dst = wob; off = g - S3; }
        float4 v = ((const float4*)src)[off];
        ushortx4 h = { f2bf(v.x), f2bf(v.y), f2bf(v.z), f2bf(v.w) };
        ((ushortx4*)dst)[off] = h;
    }
}

// ---------------------------------------------------------------------------
// Fused QKV projection + RoPE, bf16 NT-GEMM, BM=128 BN=64, 4 waves (64x32 ea).
// XOR-swizzled LDS + depth-1 double-buffered K-loop.
// nt 0..31 -> Q (RoPE, pre-scaled), 32..39 -> K (RoPE), 40..47 -> V.
// V stored transposed AND key-bit-permuted (swap bits 2<->3 of seq index).
// ---------------------------------------------------------------------------
__global__ __launch_bounds__(256)
void qkv_rope(const ushort_t* __restrict__ xb,
              const ushort_t* __restrict__ wqb, const ushort_t* __restrict__ wkb,
              const ushort_t* __restrict__ wvb,
              ushort_t* __restrict__ Qb, ushort_t* __restrict__ Kb,
              ushort_t* __restrict__ VtG,
              const float* __restrict__ cosp, const float* __restrict__ sinp)
{
    __shared__ ushort_t As[2][128 * 64];
    __shared__ ushort_t Bs[2][64 * 64];

    const int nt = blockIdx.x;                 // 0..47
    const ushort_t* Bw; int bn0; int seg;
    if (nt < 32)      { seg = 0; Bw = wqb; bn0 = nt * 64; }
    else if (nt < 40) { seg = 1; Bw = wkb; bn0 = (nt - 32) * 64; }
    else              { seg = 2; Bw = wvb; bn0 = (nt - 40) * 64; }

    const int tid  = threadIdx.x;
    const int lane = tid & 63;
    const int wid  = tid >> 6;
    const int wr = wid >> 1, wc = wid & 1;     // wave = 64 rows x 32 cols
    const int bm0 = blockIdx.y * 128;
    const int g16 = lane >> 4, l16 = lane & 15;
    const int sr  = tid >> 3;                       // stage row 0..31
    const int scb = (tid & 7) * 16;                 // stage col byte
    const int scsw = (scb ^ ((sr & 7) << 4)) >> 1;  // pre-swizzled src col
    const int xorb = (l16 & 7) << 4;                // read-side XOR

    f32x4 acc[4][2] = {};

    auto STAGE = [&](int k0, int b) {
#pragma unroll
        for (int i = 0; i < 4; i++) {
            int r = sr + i * 32;
            gload16(xb + (size_t)(bm0 + r) * DIM + k0 + scsw, &As[b][(i * 256 + tid) * 8]);
        }
#pragma unroll
        for (int i = 0; i < 2; i++) {
            int r = sr + i * 32;
            gload16(Bw + (size_t)(bn0 + r) * DIM + k0 + scsw, &Bs[b][(i * 256 + tid) * 8]);
        }
    };

    STAGE(0, 0);

    for (int k0 = 0; k0 < DIM; k0 += 64) {
        const int b = (k0 >> 6) & 1;
        __syncthreads();                             // buf b ready
        if (k0 + 64 < DIM) STAGE(k0 + 64, b ^ 1);    // prefetch next K-step
#pragma unroll
        for (int kk = 0; kk < 2; kk++) {
            const int ci = ((kk * 64 + g16 * 16) ^ xorb) >> 1;
            bf16x8 af[4], bfr[2];
#pragma unroll
            for (int mi = 0; mi < 4; mi++)
                af[mi] = *(const bf16x8*)&As[b][(wr * 64 + mi * 16 + l16) * 64 + ci];
#pragma unroll
            for (int ni = 0; ni < 2; ni++)
                bfr[ni] = *(const bf16x8*)&Bs[b][(wc * 32 + ni * 16 + l16) * 64 + ci];
#pragma unroll
            for (int mi = 0; mi < 4; mi++)
#pragma unroll
                for (int ni = 0; ni < 2; ni++)
                    acc[mi][ni] = mfma16(af[mi], bfr[ni], acc[mi][ni]);
        }
    }

#pragma unroll
    for (int mi = 0; mi < 4; mi++) {
#pragma unroll
        for (int ni = 0; ni < 2; ni++) {
            const int row0 = bm0 + wr * 64 + mi * 16 + g16 * 4;
            const int col  = bn0 + wc * 32 + ni * 16 + l16;
            f32x4 v = acc[mi][ni];
            if (seg <= 1) {
                ushort_t* C = (seg == 0) ? Qb : Kb;
                const int ldC = (seg == 0) ? NH * HD : NKV * HD;
                const int d   = col & (HD - 1);
                const int p   = d >> 1;
                const bool odd = d & 1;
#pragma unroll
                for (int r = 0; r < 4; r++) {
                    float val = v[r];
                    float partner = __shfl_xor(val, 1);
                    int m = row0 + r;
                    float c = cosp[m * (HD / 2) + p];
                    float s = sinp[m * (HD / 2) + p];
                    float o = odd ? (partner * s + val * c) : (val * c - partner * s);
                    if (seg == 0) o *= QSCALE;
                    C[(size_t)m * ldC + col] = f2bf(o);
                }
            } else {
                // V^T store with key-permutation: seq index bits 2<->3 swapped
                const int pg = ((g16 & 1) << 1) | (g16 >> 1);
                const int rowp = bm0 + wr * 64 + mi * 16 + pg * 4;
                ushortx4 hv = { f2bf(v[0]), f2bf(v[1]), f2bf(v[2]), f2bf(v[3]) };
                *(ushortx4*)&VtG[(size_t)col * SEQ + rowp] = hv;
            }
        }
    }
}

// ---------------------------------------------------------------------------
// Flash-style causal GQA attention, swapped-QK^T 32x32x16, in-register P,
// SPLIT-K partials (absolute exp2 domain -> partials combine by addition).
// 4 waves x 32 q-rows; uniform <=8-k-tile chunks. hexp2 = raw v_exp_f32.
// bf16 partials. Single-chunk blocks (qi<4) write Ab directly. Multi-chunk
// (h,qi) groups use a device-scope ticket: the LAST finishing chunk block
// reduces all partials and writes Ab (attn_reduce kernel eliminated).
// ---------------------------------------------------------------------------
__global__ __launch_bounds__(256)
void attn_fwd(const ushort_t* __restrict__ Q,
              const ushort_t* __restrict__ K,
              const ushort_t* __restrict__ VtG,
              ushort_t* __restrict__ Opart, float* __restrict__ Lpart,
              ushort_t* __restrict__ Ab, int* __restrict__ ticket)
{
    __shared__ ushort_t Ks[2][64 * 64];
    __shared__ ushort_t Vt[2][64 * 64];   // Vt[d][key-permuted]
    __shared__ int lastflag;

    const int h  = blockIdx.x;           // 0..31
    const int kh = h >> 2;               // GQA group of 4
    int y = blockIdx.y, qi = 0, pref = 0;
    for (;;) {
        int nch = (2 * qi + 9) >> 3;     // ceil((2qi+2)/8)
        if (y < nch) break;
        y -= nch; pref += nch; qi++;
    }
    const int c = y;
    const int nchq = (2 * qi + 9) >> 3;
    const int kt0 = c * CHUNK;
    const int ktN = min(kt0 + CHUNK, 2 * qi + 2);
    const int sbase0 = h * SLOTS_PER_H + pref;
    const int sidx = sbase0 + c;

    const int tid = threadIdx.x;
    const int lane = tid & 63;
    const int w = tid >> 6;              // 0..3
    const int l32 = lane & 31;
    const int hi  = lane >> 5;
    const int sr = tid >> 3;             // stage row 0..31
    const int scb = (tid & 7) * 16;      // stage col BYTE within 128B row
    const int scsw = (scb ^ ((sr & 7) << 4)) >> 1;  // pre-swizzled src col
    const int rx = (l32 & 7) << 4;       // read-side XOR byte offset

    const int qw = qi * 128 + w * 32;

    bf16x8 qf[4];
#pragma unroll
    for (int ds = 0; ds < 4; ds++)
        qf[ds] = *(const bf16x8*)&Q[(size_t)(qw + l32) * (NH * HD) + h * HD + ds * 16 + hi * 8];

    f32x16 accO0 = {}, accO1 = {};
    float lsum = 0.f;

    auto STAGE = [&](int kt, int bf) {
#pragma unroll
        for (int i = 0; i < 2; i++) {
            int row = sr + i * 32;
            gload16(K   + (size_t)(kt * 64 + row) * (NKV * HD) + kh * HD + scsw,
                    &Ks[bf][(i * 256 + tid) * 8]);
            gload16(VtG + (size_t)(kh * HD + row) * SEQ + kt * 64 + scsw,
                    &Vt[bf][(i * 256 + tid) * 8]);
        }
    };

    STAGE(kt0, 0);

    for (int kj = kt0; kj < ktN; kj++) {
        const int b = (kj - kt0) & 1;
        const int kb = kj * 64;
        __syncthreads();                          // drains vmcnt: buf b ready
        if (kj + 1 < ktN) STAGE(kj + 1, b ^ 1);   // prefetch hides under compute

        if (kb <= qw + 31) {                      // wave-uniform causal early-out
            f32x16 s0 = {}, s1 = {};
            __builtin_amdgcn_s_setprio(1);
#pragma unroll
            for (int ds = 0; ds < 4; ds++) {
                const int ci = (((32 * ds + 16 * hi)) ^ rx) >> 1;
                bf16x8 kf0 = *(const bf16x8*)&Ks[b][(l32)      * 64 + ci];
                bf16x8 kf1 = *(const bf16x8*)&Ks[b][(32 + l32) * 64 + ci];
                s0 = mfma32(kf0, qf[ds], s0);
                s1 = mfma32(kf1, qf[ds], s1);
            }
            __builtin_amdgcn_s_setprio(0);

            if (kb + 63 > qw) {
                const int qg = qw + l32;
#pragma unroll
                for (int r = 0; r < 16; r++) {
                    const int kl = (r & 3) + 8 * (r >> 2) + 4 * hi;
                    if (kb + kl > qg)      s0[r] = -1e30f;
                    if (kb + 32 + kl > qg) s1[r] = -1e30f;
                }
            }

            float p0[16], p1[16];
#pragma unroll
            for (int r = 0; r < 16; r++) { p0[r] = hexp2(s0[r]); p1[r] = hexp2(s1[r]); }
#pragma unroll
            for (int r = 0; r < 16; r++) lsum += p0[r] + p1[r];
            bf16x8 pa00, pa01, pa10, pa11;
#pragma unroll
            for (int e = 0; e < 8; e++) {
                pa00[e] = (__bf16)p0[e];  pa01[e] = (__bf16)p0[8 + e];
                pa10[e] = (__bf16)p1[e];  pa11[e] = (__bf16)p1[8 + e];
            }

            __builtin_amdgcn_s_setprio(1);
#pragma unroll
            for (int s = 0; s < 4; s++) {
                bf16x8 pa = (s == 0) ? pa00 : (s == 1) ? pa01 : (s == 2) ? pa10 : pa11;
                const int ci = (((32 * s + 16 * hi)) ^ rx) >> 1;
                bf16x8 vf0 = *(const bf16x8*)&Vt[b][(l32)      * 64 + ci];
                bf16x8 vf1 = *(const bf16x8*)&Vt[b][(32 + l32) * 64 + ci];
                accO0 = mfma32(pa, vf0, accO0);
                accO1 = mfma32(pa, vf1, accO1);
            }
            __builtin_amdgcn_s_setprio(0);
        }
    }

    lsum += __shfl_xor(lsum, 32);

    if (nchq == 1) {
        // single chunk: this partial IS the result -- normalize, write Ab
#pragma unroll
        for (int r = 0; r < 16; r++) {
            const int qr = (r & 3) + 8 * (r >> 2) + 4 * hi;
            float ls = __shfl(lsum, qr);
            float inv = 1.0f / ls;
            size_t base = (size_t)(qw + qr) * (NH * HD) + h * HD;
            Ab[base + l32]      = f2bf(accO0[r] * inv);
            Ab[base + 32 + l32] = f2bf(accO1[r] * inv);
        }
        return;
    }

    // multi-chunk: write partial, then ticket; last block reduces.
    {
        ushort_t* op = Opart + (size_t)sidx * (128 * 64);
#pragma unroll
        for (int r = 0; r < 16; r++) {
            const int qr = (r & 3) + 8 * (r >> 2) + 4 * hi;
            ushort_t* rowp = op + (size_t)(w * 32 + qr) * 64;
            rowp[l32]      = f2bf(accO0[r]);
            rowp[32 + l32] = f2bf(accO1[r]);
        }
        if (hi == 0) Lpart[sidx * 128 + w * 32 + l32] = lsum;
    }
    __threadfence();          // release: make this block's partial visible
    __syncthreads();
    if (tid == 0) {
        int old = atomicAdd(&ticket[h * 16 + qi], 1);
        lastflag = (old == nchq - 1);
    }
    __syncthreads();
    if (!lastflag) return;
    __threadfence();          // acquire: other blocks' partials now visible

    // last block: reduce all nchq partials for this (h, qi), write Ab.
    {
        const int rr = tid >> 1;             // 0..127
        const int c0 = (tid & 1) * 32;       // 0 or 32
        float l = 0.f;
        for (int c2 = 0; c2 < nchq; c2++)
            l += Lpart[(sbase0 + c2) * 128 + rr];
        const float inv = 1.0f / l;
#pragma unroll
        for (int s8 = 0; s8 < 4; s8++) {
            float sa[8] = {};
            for (int c2 = 0; c2 < nchq; c2++) {
                const ushort_t* rowp =
                    Opart + ((size_t)(sbase0 + c2) * 128 + rr) * 64 + c0 + s8 * 8;
                ushortx8 v = *(const ushortx8*)rowp;
#pragma unroll
                for (int e = 0; e < 8; e++) sa[e] += bf2f(v[e]);
            }
            ushortx8 o;
#pragma unroll
            for (int e = 0; e < 8; e++) o[e] = f2bf(sa[e] * inv);
            *(ushortx8*)&Ab[(size_t)(qi * 128 + rr) * (NH * HD) + h * 64 + c0 + s8 * 8] = o;
        }
    }
}

// ---------------------------------------------------------------------------
// Output projection: out[m][n] = sum_k attn[m][k] * wo[n][k], fp32 store.
// BM=128 BN=64, 4 waves. XOR-swizzled LDS + depth-1 double-buffered K-loop.
// ---------------------------------------------------------------------------
__global__ __launch_bounds__(256)
void gemm_out(const ushort_t* __restrict__ A, const ushort_t* __restrict__ Bw,
              float* __restrict__ C)
{
    __shared__ ushort_t As[2][128 * 64];
    __shared__ ushort_t Bs[2][64 * 64];

    const int tid  = threadIdx.x;
    const int lane = tid & 63;
    const int wid  = tid >> 6;
    const int wr = wid >> 1, wc = wid & 1;     // wave = 64 rows x 32 cols
    const int bm0 = blockIdx.y * 128, bn0 = blockIdx.x * 64;
    const int g16 = lane >> 4, l16 = lane & 15;
    const int sr  = tid >> 3;
    const int scb = (tid & 7) * 16;
    const int scsw = (scb ^ ((sr & 7) << 4)) >> 1;
    const int xorb = (l16 & 7) << 4;

    f32x4 acc[4][2] = {};

    auto STAGE = [&](int k0, int b) {
#pragma unroll
        for (int i = 0; i < 4; i++) {
            int r = sr + i * 32;
            gload16(A + (size_t)(bm0 + r) * DIM + k0 + scsw, &As[b][(i * 256 + tid) * 8]);
        }
#pragma unroll
        for (int i = 0; i < 2; i++) {
            int r = sr + i * 32;
            gload16(Bw + (size_t)(bn0 + r) * DIM + k0 + scsw, &Bs[b][(i * 256 + tid) * 8]);
        }
    };

    STAGE(0, 0);

    for (int k0 = 0; k0 < DIM; k0 += 64) {
        const int b = (k0 >> 6) & 1;
        __syncthreads();
        if (k0 + 64 < DIM) STAGE(k0 + 64, b ^ 1);
#pragma unroll
        for (int kk = 0; kk < 2; kk++) {
            const int ci = ((kk * 64 + g16 * 16) ^ xorb) >> 1;
            bf16x8 af[4], bfr[2];
#pragma unroll
            for (int mi = 0; mi < 4; mi++)
                af[mi] = *(const bf16x8*)&As[b][(wr * 64 + mi * 16 + l16) * 64 + ci];
#pragma unroll
            for (int ni = 0; ni < 2; ni++)
                bfr[ni] = *(const bf16x8*)&Bs[b][(wc * 32 + ni * 16 + l16) * 64 + ci];
#pragma unroll
            for (int mi = 0; mi < 4; mi++)
#pragma unroll
                for (int ni = 0; ni < 2; ni++)
                    acc[mi][ni] = mfma16(af[mi], bfr[ni], acc[mi][ni]);
        }
    }

#pragma unroll
    for (int mi = 0; mi < 4; mi++) {
#pragma unroll
        for (int ni = 0; ni < 2; ni++) {
            const int row0 = bm0 + wr * 64 + mi * 16 + g16 * 4;
            const int col  = bn0 + wc * 32 + ni * 16 + l16;
#pragma unroll
            for (int r = 0; r < 4; r++)
                C[(size_t)(row0 + r) * DIM + col] = acc[mi][ni][r];
        }
    }
}

extern "C" void kernel_launch(void* const* d_in, const int* in_sizes, int n_in,
                              void* d_out, int out_size, void* d_ws, size_t ws_size,
                              hipStream_t stream)
{
    (void)in_sizes; (void)n_in; (void)out_size; (void)ws_size;
    const float* x    = (const float*)d_in[0];
    const float* fcos = (const float*)d_in[1];
    const float* fsin = (const float*)d_in[2];
    const float* wq   = (const float*)d_in[3];
    const float* wk   = (const float*)d_in[4];
    const float* wv   = (const float*)d_in[5];
    const float* wo   = (const float*)d_in[6];
    float* out = (float*)d_out;

    char* ws = (char*)d_ws;
    size_t off = 0;
    ushort_t* xb  = (ushort_t*)(ws + off); off += (size_t)NX  * 2;
    ushort_t* wqb = (ushort_t*)(ws + off); off += (size_t)NWQ * 2;
    ushort_t* wkb = (ushort_t*)(ws + off); off += (size_t)NWK * 2;
    ushort_t* wvb = (ushort_t*)(ws + off); off += (size_t)NWK * 2;
    ushort_t* wob = (ushort_t*)(ws + off); off += (size_t)NWO * 2;
    ushort_t* Qb  = (ushort_t*)(ws + off); off += (size_t)SEQ * NH * HD * 2;
    ushort_t* Kb  = (ushort_t*)(ws + off); off += (size_t)SEQ * NKV * HD * 2;
    ushort_t* VtG = (ushort_t*)(ws + off); off += (size_t)SEQ * NKV * HD * 2;
    ushort_t* Ab  = (ushort_t*)(ws + off); off += (size_t)SEQ * NH * HD * 2;
    ushort_t* Opart = (ushort_t*)(ws + off); off += (size_t)32 * SLOTS_PER_H * 128 * 64 * 2;
    float* Lpart  = (float*)(ws + off);      off += (size_t)32 * SLOTS_PER_H * 128 * 4;
    int* ticket   = (int*)(ws + off);        off += (size_t)32 * 16 * 4;

    hipMemsetAsync(ticket, 0, 32 * 16 * 4, stream);

    dim3 blk(256);
    cvt5<<<dim3(2048), blk, 0, stream>>>(x, wq, wk, wv, wo, xb, wqb, wkb, wvb, wob);
    qkv_rope<<<dim3(48, 16), blk, 0, stream>>>(xb, wqb, wkb, wvb, Qb, Kb, VtG, fcos, fsin);
    attn_fwd<<<dim3(32, SLOTS_PER_H), blk, 0, stream>>>(Qb, Kb, VtG, Opart, Lpart, Ab, ticket);
    gemm_out<<<dim3(32, 16), blk, 0, stream>>>(Ab, wob, out);
}

// Round 17
// 123.532 us; speedup vs baseline: 2.5257x; 2.5257x over previous
//
#include <hip/hip_runtime.h>
#include <hip/hip_bf16.h>

#define DIM 2048
#define SEQ 2048
#define HD 64
#define NH 32
#define NKV 8

typedef __bf16 bf16x8 __attribute__((ext_vector_type(8)));
typedef __bf16 bf16x4 __attribute__((ext_vector_type(4)));
typedef float f32x4 __attribute__((ext_vector_type(4)));
typedef float f32x16 __attribute__((ext_vector_type(16)));
typedef unsigned short ushortx8 __attribute__((ext_vector_type(8)));
typedef unsigned short ushortx4 __attribute__((ext_vector_type(4)));
typedef unsigned short ushort_t;

// Q pre-scale: 1/sqrt(64) * log2(e)  -> scores come out in exp2 domain
#define QSCALE 0.1803368801111f

// split-K chunking: 8 k-tiles (512 keys) per block; 128-row q-tiles
#define CHUNK 8
#define SLOTS_PER_H 40   // sum over qi=0..15 of ceil((2qi+2)/8)

// raw v_exp_f32 (single HW transcendental), not the ~30-instr OCML exp2f.
__device__ __forceinline__ float hexp2(float x) {
    return __builtin_amdgcn_exp2f(x);
}

__device__ __forceinline__ unsigned short f2bf(float f) {
    unsigned int u = __builtin_bit_cast(unsigned int, f);
    u = (u + 0x7FFFu + ((u >> 16) & 1u)) >> 16;   // round-to-nearest-even
    return (unsigned short)u;
}
__device__ __forceinline__ float bf2f(unsigned short h) {
    return __builtin_bit_cast(float, (unsigned int)h << 16);
}

__device__ __forceinline__ f32x4 mfma16(bf16x8 a, bf16x8 b, f32x4 c) {
    return __builtin_amdgcn_mfma_f32_16x16x32_bf16(a, b, c, 0, 0, 0);
}
__device__ __forceinline__ f32x16 mfma32(bf16x8 a, bf16x8 b, f32x16 c) {
    return __builtin_amdgcn_mfma_f32_32x32x16_bf16(a, b, c, 0, 0, 0);
}

// async global->LDS, 16 bytes per lane. LDS dest must be lane-contiguous.
__device__ __forceinline__ void gload16(const ushort_t* g, ushort_t* l) {
    __builtin_amdgcn_global_load_lds(
        (const __attribute__((address_space(1))) unsigned int*)g,
        (__attribute__((address_space(3))) unsigned int*)l, 16, 0, 0);
}

// ---------------------------------------------------------------------------
// fp32 -> bf16 conversion of all GEMM operands (one pass, memory-bound)
// ---------------------------------------------------------------------------
#define NX  (SEQ * DIM)
#define NWQ (DIM * DIM)
#define NWK (NKV * HD * DIM)
#define NWO (DIM * NH * HD)

__global__ __launch_bounds__(256)
void cvt5(const float* __restrict__ x, const float* __restrict__ wq,
          const float* __restrict__ wk, const float* __restrict__ wv,
          const float* __restrict__ wo,
          ushort_t* __restrict__ xb, ushort_t* __restrict__ wqb,
          ushort_t* __restrict__ wkb, ushort_t* __restrict__ wvb,
          ushort_t* __restrict__ wob)
{
    const int S0 = NX / 4, S1 = S0 + NWQ / 4, S2 = S1 + NWK / 4,
              S3 = S2 + NWK / 4, S4 = S3 + NWO / 4;
    for (int g = blockIdx.x * blockDim.x + threadIdx.x; g < S4;
         g += gridDim.x * blockDim.x) {
        const float* src; ushort_t* dst; int off;
        if (g < S0)      { src = x;  dst = xb;  off = g; }
        else if (g < S1) { src = wq; dst = wqb; off = g - S0; }
        else if (g < S2) { src = wk; dst = wkb; off = g - S1; }
        else if (g < S3) { src = wv; dst = wvb; off = g - S2; }
        else             { src = wo; dst = wob; off = g - S3; }
        float4 v = ((const float4*)src)[off];
        ushortx4 h = { f2bf(v.x), f2bf(v.y), f2bf(v.z), f2bf(v.w) };
        ((ushortx4*)dst)[off] = h;
    }
}

// ---------------------------------------------------------------------------
// Fused QKV projection + RoPE, bf16 NT-GEMM, BM=128 BN=64, 4 waves (64x32 ea).
// XOR-swizzled LDS + depth-1 double-buffered K-loop.
// nt 0..31 -> Q (RoPE, pre-scaled), 32..39 -> K (RoPE), 40..47 -> V.
// V stored transposed AND key-bit-permuted (swap bits 2<->3 of seq index).
// ---------------------------------------------------------------------------
__global__ __launch_bounds__(256)
void qkv_rope(const ushort_t* __restrict__ xb,
              const ushort_t* __restrict__ wqb, const ushort_t* __restrict__ wkb,
              const ushort_t* __restrict__ wvb,
              ushort_t* __restrict__ Qb, ushort_t* __restrict__ Kb,
              ushort_t* __restrict__ VtG,
              const float* __restrict__ cosp, const float* __restrict__ sinp)
{
    __shared__ ushort_t As[2][128 * 64];
    __shared__ ushort_t Bs[2][64 * 64];

    const int nt = blockIdx.x;                 // 0..47
    const ushort_t* Bw; int bn0; int seg;
    if (nt < 32)      { seg = 0; Bw = wqb; bn0 = nt * 64; }
    else if (nt < 40) { seg = 1; Bw = wkb; bn0 = (nt - 32) * 64; }
    else              { seg = 2; Bw = wvb; bn0 = (nt - 40) * 64; }

    const int tid  = threadIdx.x;
    const int lane = tid & 63;
    const int wid  = tid >> 6;
    const int wr = wid >> 1, wc = wid & 1;     // wave = 64 rows x 32 cols
    const int bm0 = blockIdx.y * 128;
    const int g16 = lane >> 4, l16 = lane & 15;
    const int sr  = tid >> 3;                       // stage row 0..31
    const int scb = (tid & 7) * 16;                 // stage col byte
    const int scsw = (scb ^ ((sr & 7) << 4)) >> 1;  // pre-swizzled src col
    const int xorb = (l16 & 7) << 4;                // read-side XOR

    f32x4 acc[4][2] = {};

    auto STAGE = [&](int k0, int b) {
#pragma unroll
        for (int i = 0; i < 4; i++) {
            int r = sr + i * 32;
            gload16(xb + (size_t)(bm0 + r) * DIM + k0 + scsw, &As[b][(i * 256 + tid) * 8]);
        }
#pragma unroll
        for (int i = 0; i < 2; i++) {
            int r = sr + i * 32;
            gload16(Bw + (size_t)(bn0 + r) * DIM + k0 + scsw, &Bs[b][(i * 256 + tid) * 8]);
        }
    };

    STAGE(0, 0);

    for (int k0 = 0; k0 < DIM; k0 += 64) {
        const int b = (k0 >> 6) & 1;
        __syncthreads();                             // buf b ready
        if (k0 + 64 < DIM) STAGE(k0 + 64, b ^ 1);    // prefetch next K-step
#pragma unroll
        for (int kk = 0; kk < 2; kk++) {
            const int ci = ((kk * 64 + g16 * 16) ^ xorb) >> 1;
            bf16x8 af[4], bfr[2];
#pragma unroll
            for (int mi = 0; mi < 4; mi++)
                af[mi] = *(const bf16x8*)&As[b][(wr * 64 + mi * 16 + l16) * 64 + ci];
#pragma unroll
            for (int ni = 0; ni < 2; ni++)
                bfr[ni] = *(const bf16x8*)&Bs[b][(wc * 32 + ni * 16 + l16) * 64 + ci];
#pragma unroll
            for (int mi = 0; mi < 4; mi++)
#pragma unroll
                for (int ni = 0; ni < 2; ni++)
                    acc[mi][ni] = mfma16(af[mi], bfr[ni], acc[mi][ni]);
        }
    }

#pragma unroll
    for (int mi = 0; mi < 4; mi++) {
#pragma unroll
        for (int ni = 0; ni < 2; ni++) {
            const int row0 = bm0 + wr * 64 + mi * 16 + g16 * 4;
            const int col  = bn0 + wc * 32 + ni * 16 + l16;
            f32x4 v = acc[mi][ni];
            if (seg <= 1) {
                ushort_t* C = (seg == 0) ? Qb : Kb;
                const int ldC = (seg == 0) ? NH * HD : NKV * HD;
                const int d   = col & (HD - 1);
                const int p   = d >> 1;
                const bool odd = d & 1;
#pragma unroll
                for (int r = 0; r < 4; r++) {
                    float val = v[r];
                    float partner = __shfl_xor(val, 1);
                    int m = row0 + r;
                    float c = cosp[m * (HD / 2) + p];
                    float s = sinp[m * (HD / 2) + p];
                    float o = odd ? (partner * s + val * c) : (val * c - partner * s);
                    if (seg == 0) o *= QSCALE;
                    C[(size_t)m * ldC + col] = f2bf(o);
                }
            } else {
                // V^T store with key-permutation: seq index bits 2<->3 swapped
                const int pg = ((g16 & 1) << 1) | (g16 >> 1);
                const int rowp = bm0 + wr * 64 + mi * 16 + pg * 4;
                ushortx4 hv = { f2bf(v[0]), f2bf(v[1]), f2bf(v[2]), f2bf(v[3]) };
                *(ushortx4*)&VtG[(size_t)col * SEQ + rowp] = hv;
            }
        }
    }
}

// ---------------------------------------------------------------------------
// Flash-style causal GQA attention, swapped-QK^T 32x32x16, in-register P,
// SPLIT-K partials (absolute exp2 domain -> partials combine by addition).
// 4 waves x 32 q-rows; uniform <=8-k-tile chunks. hexp2 = raw v_exp_f32.
// Partials stored bf16 (halved traffic). Single-chunk blocks (qi<4) write
// the normalized result straight to Ab and skip the partial round-trip.
// ---------------------------------------------------------------------------
__global__ __launch_bounds__(256)
void attn_fwd(const ushort_t* __restrict__ Q,
              const ushort_t* __restrict__ K,
              const ushort_t* __restrict__ VtG,
              ushort_t* __restrict__ Opart, float* __restrict__ Lpart,
              ushort_t* __restrict__ Ab)
{
    __shared__ ushort_t Ks[2][64 * 64];
    __shared__ ushort_t Vt[2][64 * 64];   // Vt[d][key-permuted]

    const int h  = blockIdx.x;           // 0..31
    const int kh = h >> 2;               // GQA group of 4
    int y = blockIdx.y, qi = 0, pref = 0;
    for (;;) {
        int nch = (2 * qi + 9) >> 3;     // ceil((2qi+2)/8)
        if (y < nch) break;
        y -= nch; pref += nch; qi++;
    }
    const int c = y;
    const int nchq = (2 * qi + 9) >> 3;
    const int kt0 = c * CHUNK;
    const int ktN = min(kt0 + CHUNK, 2 * qi + 2);
    const int sidx = h * SLOTS_PER_H + pref + c;

    const int tid = threadIdx.x;
    const int lane = tid & 63;
    const int w = tid >> 6;              // 0..3
    const int l32 = lane & 31;
    const int hi  = lane >> 5;
    const int sr = tid >> 3;             // stage row 0..31
    const int scb = (tid & 7) * 16;      // stage col BYTE within 128B row
    const int scsw = (scb ^ ((sr & 7) << 4)) >> 1;  // pre-swizzled src col
    const int rx = (l32 & 7) << 4;       // read-side XOR byte offset

    const int qw = qi * 128 + w * 32;

    bf16x8 qf[4];
#pragma unroll
    for (int ds = 0; ds < 4; ds++)
        qf[ds] = *(const bf16x8*)&Q[(size_t)(qw + l32) * (NH * HD) + h * HD + ds * 16 + hi * 8];

    f32x16 accO0 = {}, accO1 = {};
    float lsum = 0.f;

    auto STAGE = [&](int kt, int bf) {
#pragma unroll
        for (int i = 0; i < 2; i++) {
            int row = sr + i * 32;
            gload16(K   + (size_t)(kt * 64 + row) * (NKV * HD) + kh * HD + scsw,
                    &Ks[bf][(i * 256 + tid) * 8]);
            gload16(VtG + (size_t)(kh * HD + row) * SEQ + kt * 64 + scsw,
                    &Vt[bf][(i * 256 + tid) * 8]);
        }
    };

    STAGE(kt0, 0);

    for (int kj = kt0; kj < ktN; kj++) {
        const int b = (kj - kt0) & 1;
        const int kb = kj * 64;
        __syncthreads();                          // drains vmcnt: buf b ready
        if (kj + 1 < ktN) STAGE(kj + 1, b ^ 1);   // prefetch hides under compute

        if (kb <= qw + 31) {                      // wave-uniform causal early-out
            f32x16 s0 = {}, s1 = {};
            __builtin_amdgcn_s_setprio(1);
#pragma unroll
            for (int ds = 0; ds < 4; ds++) {
                const int ci = (((32 * ds + 16 * hi)) ^ rx) >> 1;
                bf16x8 kf0 = *(const bf16x8*)&Ks[b][(l32)      * 64 + ci];
                bf16x8 kf1 = *(const bf16x8*)&Ks[b][(32 + l32) * 64 + ci];
                s0 = mfma32(kf0, qf[ds], s0);
                s1 = mfma32(kf1, qf[ds], s1);
            }
            __builtin_amdgcn_s_setprio(0);

            if (kb + 63 > qw) {
                const int qg = qw + l32;
#pragma unroll
                for (int r = 0; r < 16; r++) {
                    const int kl = (r & 3) + 8 * (r >> 2) + 4 * hi;
                    if (kb + kl > qg)      s0[r] = -1e30f;
                    if (kb + 32 + kl > qg) s1[r] = -1e30f;
                }
            }

            float p0[16], p1[16];
#pragma unroll
            for (int r = 0; r < 16; r++) { p0[r] = hexp2(s0[r]); p1[r] = hexp2(s1[r]); }
#pragma unroll
            for (int r = 0; r < 16; r++) lsum += p0[r] + p1[r];
            bf16x8 pa00, pa01, pa10, pa11;
#pragma unroll
            for (int e = 0; e < 8; e++) {
                pa00[e] = (__bf16)p0[e];  pa01[e] = (__bf16)p0[8 + e];
                pa10[e] = (__bf16)p1[e];  pa11[e] = (__bf16)p1[8 + e];
            }

            __builtin_amdgcn_s_setprio(1);
#pragma unroll
            for (int s = 0; s < 4; s++) {
                bf16x8 pa = (s == 0) ? pa00 : (s == 1) ? pa01 : (s == 2) ? pa10 : pa11;
                const int ci = (((32 * s + 16 * hi)) ^ rx) >> 1;
                bf16x8 vf0 = *(const bf16x8*)&Vt[b][(l32)      * 64 + ci];
                bf16x8 vf1 = *(const bf16x8*)&Vt[b][(32 + l32) * 64 + ci];
                accO0 = mfma32(pa, vf0, accO0);
                accO1 = mfma32(pa, vf1, accO1);
            }
            __builtin_amdgcn_s_setprio(0);
        }
    }

    lsum += __shfl_xor(lsum, 32);

    if (nchq == 1) {
        // single chunk: this partial IS the result -- normalize, write Ab
#pragma unroll
        for (int r = 0; r < 16; r++) {
            const int qr = (r & 3) + 8 * (r >> 2) + 4 * hi;
            float ls = __shfl(lsum, qr);
            float inv = 1.0f / ls;
            size_t base = (size_t)(qw + qr) * (NH * HD) + h * HD;
            Ab[base + l32]      = f2bf(accO0[r] * inv);
            Ab[base + 32 + l32] = f2bf(accO1[r] * inv);
        }
    } else {
        ushort_t* op = Opart + (size_t)sidx * (128 * 64);
#pragma unroll
        for (int r = 0; r < 16; r++) {
            const int qr = (r & 3) + 8 * (r >> 2) + 4 * hi;
            ushort_t* rowp = op + (size_t)(w * 32 + qr) * 64;
            rowp[l32]      = f2bf(accO0[r]);
            rowp[32 + l32] = f2bf(accO1[r]);
        }
        if (hi == 0) Lpart[sidx * 128 + w * 32 + l32] = lsum;
    }
}

// ---------------------------------------------------------------------------
// split-K reduce: Ab[m][h*64+d] = sum_c Opart / sum_c lsum  (bf16 partials).
// Rows with qi<4 (single chunk) were written directly by attn_fwd -- skip.
// ---------------------------------------------------------------------------
__global__ __launch_bounds__(256)
void attn_reduce(const ushort_t* __restrict__ Opart, const float* __restrict__ Lpart,
                 ushort_t* __restrict__ Ab)
{
    const int gid = blockIdx.x * 256 + threadIdx.x;
    const int g = gid & 7;
    const int h = (gid >> 3) & 31;
    const int m = gid >> 8;              // 0..2047
    const int qi = m >> 7, rr = m & 127;
    if (qi < 4) return;                  // written directly by attn_fwd
    int pref = 0;
#pragma unroll
    for (int q = 0; q < 16; q++) pref += (q < qi) ? ((2 * q + 9) >> 3) : 0;
    const int nch = (2 * qi + 9) >> 3;
    const int sbase = h * SLOTS_PER_H + pref;

    float sa[8] = {};
    float l = 0.f;
    for (int c = 0; c < nch; c++) {
        const ushort_t* rowp = Opart + ((size_t)(sbase + c) * 128 + rr) * 64 + g * 8;
        ushortx8 v = *(const ushortx8*)rowp;
#pragma unroll
        for (int e = 0; e < 8; e++) sa[e] += bf2f(v[e]);
        l += Lpart[(sbase + c) * 128 + rr];
    }
    const float inv = 1.0f / l;
    ushortx8 o;
#pragma unroll
    for (int e = 0; e < 8; e++) o[e] = f2bf(sa[e] * inv);
    *(ushortx8*)&Ab[(size_t)m * (NH * HD) + h * 64 + g * 8] = o;
}

// ---------------------------------------------------------------------------
// Output projection: out[m][n] = sum_k attn[m][k] * wo[n][k], fp32 store.
// BM=128 BN=64, 4 waves. XOR-swizzled LDS + depth-1 double-buffered K-loop.
// ---------------------------------------------------------------------------
__global__ __launch_bounds__(256)
void gemm_out(const ushort_t* __restrict__ A, const ushort_t* __restrict__ Bw,
              float* __restrict__ C)
{
    __shared__ ushort_t As[2][128 * 64];
    __shared__ ushort_t Bs[2][64 * 64];

    const int tid  = threadIdx.x;
    const int lane = tid & 63;
    const int wid  = tid >> 6;
    const int wr = wid >> 1, wc = wid & 1;     // wave = 64 rows x 32 cols
    const int bm0 = blockIdx.y * 128, bn0 = blockIdx.x * 64;
    const int g16 = lane >> 4, l16 = lane & 15;
    const int sr  = tid >> 3;
    const int scb = (tid & 7) * 16;
    const int scsw = (scb ^ ((sr & 7) << 4)) >> 1;
    const int xorb = (l16 & 7) << 4;

    f32x4 acc[4][2] = {};

    auto STAGE = [&](int k0, int b) {
#pragma unroll
        for (int i = 0; i < 4; i++) {
            int r = sr + i * 32;
            gload16(A + (size_t)(bm0 + r) * DIM + k0 + scsw, &As[b][(i * 256 + tid) * 8]);
        }
#pragma unroll
        for (int i = 0; i < 2; i++) {
            int r = sr + i * 32;
            gload16(Bw + (size_t)(bn0 + r) * DIM + k0 + scsw, &Bs[b][(i * 256 + tid) * 8]);
        }
    };

    STAGE(0, 0);

    for (int k0 = 0; k0 < DIM; k0 += 64) {
        const int b = (k0 >> 6) & 1;
        __syncthreads();
        if (k0 + 64 < DIM) STAGE(k0 + 64, b ^ 1);
#pragma unroll
        for (int kk = 0; kk < 2; kk++) {
            const int ci = ((kk * 64 + g16 * 16) ^ xorb) >> 1;
            bf16x8 af[4], bfr[2];
#pragma unroll
            for (int mi = 0; mi < 4; mi++)
                af[mi] = *(const bf16x8*)&As[b][(wr * 64 + mi * 16 + l16) * 64 + ci];
#pragma unroll
            for (int ni = 0; ni < 2; ni++)
                bfr[ni] = *(const bf16x8*)&Bs[b][(wc * 32 + ni * 16 + l16) * 64 + ci];
#pragma unroll
            for (int mi = 0; mi < 4; mi++)
#pragma unroll
                for (int ni = 0; ni < 2; ni++)
                    acc[mi][ni] = mfma16(af[mi], bfr[ni], acc[mi][ni]);
        }
    }

#pragma unroll
    for (int mi = 0; mi < 4; mi++) {
#pragma unroll
        for (int ni = 0; ni < 2; ni++) {
            const int row0 = bm0 + wr * 64 + mi * 16 + g16 * 4;
            const int col  = bn0 + wc * 32 + ni * 16 + l16;
#pragma unroll
            for (int r = 0; r < 4; r++)
                C[(size_t)(row0 + r) * DIM + col] = acc[mi][ni][r];
        }
    }
}

extern "C" void kernel_launch(void* const* d_in, const int* in_sizes, int n_in,
                              void* d_out, int out_size, void* d_ws, size_t ws_size,
                              hipStream_t stream)
{
    (void)in_sizes; (void)n_in; (void)out_size; (void)ws_size;
    const float* x    = (const float*)d_in[0];
    const float* fcos = (const float*)d_in[1];
    const float* fsin = (const float*)d_in[2];
    const float* wq   = (const float*)d_in[3];
    const float* wk   = (const float*)d_in[4];
    const float* wv   = (const float*)d_in[5];
    const float* wo   = (const float*)d_in[6];
    float* out = (float*)d_out;

    char* ws = (char*)d_ws;
    size_t off = 0;
    ushort_t* xb  = (ushort_t*)(ws + off); off += (size_t)NX  * 2;
    ushort_t* wqb = (ushort_t*)(ws + off); off += (size_t)NWQ * 2;
    ushort_t* wkb = (ushort_t*)(ws + off); off += (size_t)NWK * 2;
    ushort_t* wvb = (ushort_t*)(ws + off); off += (size_t)NWK * 2;
    ushort_t* wob = (ushort_t*)(ws + off); off += (size_t)NWO * 2;
    ushort_t* Qb  = (ushort_t*)(ws + off); off += (size_t)SEQ * NH * HD * 2;
    ushort_t* Kb  = (ushort_t*)(ws + off); off += (size_t)SEQ * NKV * HD * 2;
    ushort_t* VtG = (ushort_t*)(ws + off); off += (size_t)SEQ * NKV * HD * 2;
    ushort_t* Ab  = (ushort_t*)(ws + off); off += (size_t)SEQ * NH * HD * 2;
    ushort_t* Opart = (ushort_t*)(ws + off); off += (size_t)32 * SLOTS_PER_H * 128 * 64 * 2;
    float* Lpart  = (float*)(ws + off);      off += (size_t)32 * SLOTS_PER_H * 128 * 4;

    dim3 blk(256);
    cvt5<<<dim3(2048), blk, 0, stream>>>(x, wq, wk, wv, wo, xb, wqb, wkb, wvb, wob);
    qkv_rope<<<dim3(48, 16), blk, 0, stream>>>(xb, wqb, wkb, wvb, Qb, Kb, VtG, fcos, fsin);
    attn_fwd<<<dim3(32, SLOTS_PER_H), blk, 0, stream>>>(Qb, Kb, VtG, Opart, Lpart, Ab);
    attn_reduce<<<dim3(2048), blk, 0, stream>>>(Opart, Lpart, Ab);
    gemm_out<<<dim3(32, 16), blk, 0, stream>>>(Ab, wob, out);
}